// Round 3
// baseline (768.425 us; speedup 1.0000x reference)
//
#include <hip/hip_runtime.h>
#include <hip/hip_bf16.h>

// Problem: MultiHeadAttention  B=2, S=2048, D=1024, H=16, dk=64
// out0 = context @ Wo + bo        [B,S,1024]  fp32
// out1 = attention_weights        [B,H,S,S]   fp32

#define SEQ   2048
#define DMODEL 1024
#define NH    16
#define DKH   64

typedef __attribute__((ext_vector_type(8)))  short short8;
typedef __attribute__((ext_vector_type(4)))  float floatx4;
typedef __attribute__((ext_vector_type(16))) float floatx16;

__device__ __forceinline__ short f2bf(float f) {
    __hip_bfloat16 h = __float2bfloat16(f);
    return *reinterpret_cast<short*>(&h);
}
__device__ __forceinline__ unsigned int packbf(float a, float b) {
    return (unsigned int)(unsigned short)f2bf(a) | ((unsigned int)(unsigned short)f2bf(b) << 16);
}

// async global->LDS 16B copy. LDS dest is wave-uniform base; HW adds lane*16.
__device__ __forceinline__ void gload_lds16(const short* g, short* l) {
    __builtin_amdgcn_global_load_lds(
        (const __attribute__((address_space(1))) void*)g,
        (__attribute__((address_space(3))) void*)l, 16, 0, 0);
}

// ---------------- fp32 -> bf16 elementwise convert (q,k,v fused via z) ----------------
__global__ void conv3(const float* __restrict__ s0, const float* __restrict__ s1,
                      const float* __restrict__ s2, short* __restrict__ d0,
                      short* __restrict__ d1, short* __restrict__ d2) {
    int z = blockIdx.z;
    const float* src = z == 0 ? s0 : z == 1 ? s1 : s2;
    short* dst       = z == 0 ? d0 : z == 1 ? d1 : d2;
    int i = blockIdx.x * blockDim.x + threadIdx.x;
    float4 v = reinterpret_cast<const float4*>(src)[i];
    short4 o;
    o.x = f2bf(v.x); o.y = f2bf(v.y); o.z = f2bf(v.z); o.w = f2bf(v.w);
    reinterpret_cast<short4*>(dst)[i] = o;
}

// ---------------- W [K,N] fp32 -> Wt [N,K] bf16 (tiled transpose, 4 fused) ----------------
__global__ void conv_wt4(const float* __restrict__ W0, const float* __restrict__ W1,
                         const float* __restrict__ W2, const float* __restrict__ W3,
                         short* __restrict__ T0, short* __restrict__ T1,
                         short* __restrict__ T2, short* __restrict__ T3) {
    __shared__ short T[64 * 72];
    int z = blockIdx.z;
    const float* W = z == 0 ? W0 : z == 1 ? W1 : z == 2 ? W2 : W3;
    short* Wt      = z == 0 ? T0 : z == 1 ? T1 : z == 2 ? T2 : T3;
    int tid = threadIdx.x;
    int bk = blockIdx.y, bn = blockIdx.x;
    for (int i = 0; i < 4; i++) {
        int ch = i * 256 + tid;
        int r = ch >> 4, c4 = (ch & 15) * 4;
        float4 v = *(const float4*)&W[(size_t)(bk * 64 + r) * 1024 + bn * 64 + c4];
        T[(c4 + 0) * 72 + r] = f2bf(v.x);
        T[(c4 + 1) * 72 + r] = f2bf(v.y);
        T[(c4 + 2) * 72 + r] = f2bf(v.z);
        T[(c4 + 3) * 72 + r] = f2bf(v.w);
    }
    __syncthreads();
    for (int i = 0; i < 2; i++) {
        int ch = i * 256 + tid;
        int n = ch >> 3, k8 = (ch & 7) * 8;
        *(short8*)&Wt[(size_t)(bn * 64 + n) * 1024 + bk * 64 + k8] = *(const short8*)&T[n * 72 + k8];
    }
}

// ---------------- GEMM body: A[4096,1024]bf16 @ Bt^T + bias ----------------
// 2-phase double-buffered global_load_lds, tile 128Mx64N, BK=32.
__device__ __forceinline__ void gemm_body(
    const short* __restrict__ A, const short* __restrict__ Bt,
    const float* __restrict__ bias, void* __restrict__ dst, int mode)
{
    __shared__ __align__(16) short As[2][128 * 32];
    __shared__ __align__(16) short Bs[2][64 * 32];
    int tid = threadIdx.x;
    int wave = tid >> 6, lane = tid & 63, quad = lane >> 4, l15 = lane & 15;
    int bm = blockIdx.y, bn = blockIdx.x;

    floatx4 acc[2][4];
#pragma unroll
    for (int i = 0; i < 2; i++)
#pragma unroll
        for (int j = 0; j < 4; j++) acc[i][j] = (floatx4){0.f, 0.f, 0.f, 0.f};

    const short* aBase = &A [(size_t)(bm * 128 + (tid >> 2)) * 1024 + (tid & 3) * 8];
    const short* bBase = &Bt[(size_t)(bn * 64  + (tid >> 2)) * 1024 + (tid & 3) * 8];

#define STAGE(buf, kb) do {                                                            \
        gload_lds16(aBase + (kb) * 32,             &As[buf][(wave * 64) * 8]);         \
        gload_lds16(aBase + 64 * 1024 + (kb) * 32, &As[buf][(256 + wave * 64) * 8]);   \
        gload_lds16(bBase + (kb) * 32,             &Bs[buf][(wave * 64) * 8]);         \
    } while (0)

    STAGE(0, 0);
    __syncthreads();
    int cur = 0;
    for (int kb = 0; kb < 32; kb++) {
        if (kb < 31) STAGE(cur ^ 1, kb + 1);
        short8 ar[2], br[4];
#pragma unroll
        for (int mt = 0; mt < 2; mt++) ar[mt] = *(const short8*)&As[cur][(wave * 32 + mt * 16 + l15) * 32 + quad * 8];
#pragma unroll
        for (int nt = 0; nt < 4; nt++) br[nt] = *(const short8*)&Bs[cur][(nt * 16 + l15) * 32 + quad * 8];
#pragma unroll
        for (int mt = 0; mt < 2; mt++)
#pragma unroll
            for (int nt = 0; nt < 4; nt++)
                acc[mt][nt] = __builtin_amdgcn_mfma_f32_16x16x32_bf16(ar[mt], br[nt], acc[mt][nt], 0, 0, 0);
        __syncthreads();
        cur ^= 1;
    }
#undef STAGE

#pragma unroll
    for (int mt = 0; mt < 2; mt++) {
#pragma unroll
        for (int nt = 0; nt < 4; nt++) {
            int col = bn * 64 + nt * 16 + l15;
            float bb = bias[col];
#pragma unroll
            for (int r = 0; r < 4; r++) {
                int row = bm * 128 + wave * 32 + mt * 16 + quad * 4 + r;
                float v = acc[mt][nt][r] + bb;
                if (mode == 3) {
                    ((float*)dst)[(size_t)row * 1024 + col] = v;
                } else {
                    int b = row >> 11, s = row & 2047, h = col >> 6, dk = col & 63;
                    size_t idx;
                    if (mode == 0) idx = ((size_t)(b * NH + h) * SEQ + s) * DKH + dk;
                    else           idx = ((size_t)(b * NH + h) * DKH + dk) * SEQ + s;
                    ((short*)dst)[idx] = f2bf(v);
                }
            }
        }
    }
}

__global__ __launch_bounds__(256, 4) void gemm_qkv(
    const short* __restrict__ xq, const short* __restrict__ xk, const short* __restrict__ xv,
    const short* __restrict__ wq, const short* __restrict__ wk, const short* __restrict__ wv,
    const float* __restrict__ bq, const float* __restrict__ bk, const float* __restrict__ bv,
    short* __restrict__ qh, short* __restrict__ kh, short* __restrict__ vth)
{
    int z = blockIdx.z;
    const short* A  = z == 0 ? xq : z == 1 ? xk : xv;
    const short* Bt = z == 0 ? wq : z == 1 ? wk : wv;
    const float* bi = z == 0 ? bq : z == 1 ? bk : bv;
    short* dst      = z == 0 ? qh : z == 1 ? kh : vth;
    gemm_body(A, Bt, bi, dst, z == 2 ? 2 : 0);
}

__global__ __launch_bounds__(256, 4) void gemm_fin(
    const short* __restrict__ A, const short* __restrict__ Bt,
    const float* __restrict__ bias, float* __restrict__ dst)
{
    gemm_body(A, Bt, bias, dst, 3);
}

// ---------------- attn pass 1: barrier-free, LDS-free k-loop ----------------
// Swapped QK^T: S'[key][q] = mfma_32x32x16(A=K, B=Q). Each wave owns a 32-key
// slice per 128-key tile; P stays in registers (cross-half key exchange via
// shfl_xor(32)); PV accumulates a per-wave partial ctx over its own keys.
// Cross-wave ctx reduce + rowsum happen ONCE at the end through LDS.
// Fragment layouts (validated against the working 16x16 kernel's convention):
//   A[m][k]: lane = m%32 + 32*(k>>3), elem k&7
//   B[k][n]: lane = n%32 + 32*(k>>3), elem k&7
//   C/D    : col  = lane&31, row = (reg&3) + 8*(reg>>2) + 4*(lane>>5)
__global__ __launch_bounds__(256, 2) void attn_p1(
    const short* __restrict__ Q,    // [B,H,S,64] bf16
    const short* __restrict__ K,    // [B,H,S,64] bf16
    const short* __restrict__ Vt,   // [B,H,64,S] bf16
    float* __restrict__ rws,        // [B*H, S/64, 64] fp32 rinv out
    short* __restrict__ ctx)        // [B*S,1024] bf16
{
    __shared__ float Cs[4][64 * 68];     // per-wave ctx partial slabs (69632 B)
    __shared__ float partial[4][64];

    int tid = threadIdx.x, wave = tid >> 6, lane = tid & 63;
    int l31 = lane & 31, hh2 = lane >> 5;        // half index within wave
    int qt = blockIdx.x, bh = blockIdx.y;
    int b = bh >> 4, hd = bh & 15;

    const short* qb = Q  + ((size_t)bh * SEQ + qt * 64) * DKH;
    const short* kb = K  + (size_t)bh * SEQ * DKH;
    const short* vb = Vt + (size_t)bh * DKH * SEQ;

    // Q B-frags (resident): qf[nt][kt] = Q[q=nt*32+l31][d=kt*16+hh2*8 ..+7]
    short8 qf[2][4];
#pragma unroll
    for (int nt = 0; nt < 2; nt++)
#pragma unroll
        for (int kt = 0; kt < 4; kt++)
            qf[nt][kt] = *(const short8*)&qb[(nt * 32 + l31) * 64 + kt * 16 + hh2 * 8];

    floatx16 cacc[2][2];
#pragma unroll
    for (int i = 0; i < 2; i++)
#pragma unroll
        for (int j = 0; j < 2; j++)
#pragma unroll
            for (int r = 0; r < 16; r++) cacc[i][j][r] = 0.f;
    float rs[2] = {0.f, 0.f};

    for (int kbase = wave * 32; kbase < SEQ; kbase += 128) {
        // K A-frags: kf[kt] = K[key=kbase+l31][d=kt*16+hh2*8 ..+7]
        short8 kf[4];
#pragma unroll
        for (int kt = 0; kt < 4; kt++)
            kf[kt] = *(const short8*)&kb[(size_t)(kbase + l31) * 64 + kt * 16 + hh2 * 8];
        // V B-frags: vf[nt][s] = Vt[d=nt*32+l31][key=kbase+s*16+hh2*8 ..+7]
        short8 vf[2][2];
#pragma unroll
        for (int nt = 0; nt < 2; nt++)
#pragma unroll
            for (int s = 0; s < 2; s++)
                vf[nt][s] = *(const short8*)&vb[(size_t)(nt * 32 + l31) * SEQ + kbase + s * 16 + hh2 * 8];

        // QK^T swapped: sacc[nt] = S'[key 0..31][q = nt*32 + l31]
        floatx16 sacc[2];
#pragma unroll
        for (int nt = 0; nt < 2; nt++)
#pragma unroll
            for (int r = 0; r < 16; r++) sacc[nt][r] = 0.f;
#pragma unroll
        for (int kt = 0; kt < 4; kt++)
#pragma unroll
            for (int nt = 0; nt < 2; nt++)
                sacc[nt] = __builtin_amdgcn_mfma_f32_32x32x16_bf16(kf[kt], qf[nt][kt], sacc[nt], 0, 0, 0);

        // exp + in-register P->A-frag reshape + rowsum
        short8 pfrag[2][2];
#pragma unroll
        for (int nt = 0; nt < 2; nt++) {
            float e[16];
            float sum = 0.f;
#pragma unroll
            for (int r = 0; r < 16; r++) {
                e[r] = __expf(sacc[nt][r] * 0.125f);
                sum += e[r];
            }
            rs[nt] += sum;
            // pk[j]: keys {base_j+4h, base_j+4h+1}, base = (2j&3) + 8*(2j>>2)
            unsigned int pk[8], X[8];
#pragma unroll
            for (int j = 0; j < 8; j++) pk[j] = packbf(e[2 * j], e[2 * j + 1]);
#pragma unroll
            for (int j = 0; j < 8; j++) X[j] = __shfl_xor(pk[j], 32, 64);
#pragma unroll
            for (int s = 0; s < 2; s++) {
                unsigned int u[4];
                u[0] = hh2 ? X[4 * s + 2]  : pk[4 * s + 0];
                u[1] = hh2 ? X[4 * s + 3]  : pk[4 * s + 1];
                u[2] = hh2 ? pk[4 * s + 2] : X[4 * s + 0];
                u[3] = hh2 ? pk[4 * s + 3] : X[4 * s + 1];
                pfrag[nt][s] = *reinterpret_cast<short8*>(u);
            }
        }

        // ctx partial += P @ V over this wave's 32 keys
#pragma unroll
        for (int s = 0; s < 2; s++)
#pragma unroll
            for (int mt = 0; mt < 2; mt++)
#pragma unroll
                for (int nt = 0; nt < 2; nt++)
                    cacc[mt][nt] = __builtin_amdgcn_mfma_f32_32x32x16_bf16(pfrag[mt][s], vf[nt][s], cacc[mt][nt], 0, 0, 0);
    }

    // fold the two key-halves of the rowsum; write per-wave partials
    rs[0] += __shfl_xor(rs[0], 32, 64);
    rs[1] += __shfl_xor(rs[1], 32, 64);
    if (hh2 == 0) {
        partial[wave][l31]      = rs[0];
        partial[wave][32 + l31] = rs[1];
    }
    // dump per-wave ctx partial to its slab
    float* slab = &Cs[wave][0];
#pragma unroll
    for (int mt = 0; mt < 2; mt++)
#pragma unroll
        for (int nt = 0; nt < 2; nt++)
#pragma unroll
            for (int r = 0; r < 16; r++) {
                int q = mt * 32 + (r & 3) + 8 * (r >> 2) + 4 * hh2;
                int d = nt * 32 + l31;
                slab[q * 68 + d] = cacc[mt][nt][r];
            }
    __syncthreads();

    // final: thread -> (q = tid>>2, d0 = (tid&3)*16): sum 4 slabs, normalize, store
    int q = tid >> 2, d0 = (tid & 3) * 16;
    float rinvv = 1.f / (partial[0][q] + partial[1][q] + partial[2][q] + partial[3][q]);
    if ((tid & 3) == 0) rws[((size_t)bh * 32 + qt) * 64 + q] = rinvv;

    short ov[16];
#pragma unroll
    for (int c = 0; c < 4; c++) {
        float4 a = *(const float4*)&Cs[0][q * 68 + d0 + c * 4];
        float4 x1 = *(const float4*)&Cs[1][q * 68 + d0 + c * 4];
        float4 x2 = *(const float4*)&Cs[2][q * 68 + d0 + c * 4];
        float4 x3 = *(const float4*)&Cs[3][q * 68 + d0 + c * 4];
        ov[c * 4 + 0] = f2bf((a.x + x1.x + x2.x + x3.x) * rinvv);
        ov[c * 4 + 1] = f2bf((a.y + x1.y + x2.y + x3.y) * rinvv);
        ov[c * 4 + 2] = f2bf((a.z + x1.z + x2.z + x3.z) * rinvv);
        ov[c * 4 + 3] = f2bf((a.w + x1.w + x2.w + x3.w) * rinvv);
    }
    size_t row = (size_t)(b * SEQ + qt * 64 + q);
    *(short8*)&ctx[row * DMODEL + hd * DKH + d0]     = *(short8*)&ov[0];
    *(short8*)&ctx[row * DMODEL + hd * DKH + d0 + 8] = *(short8*)&ov[8];
}

// ---------------- attn pass 2: barrier-free weights write ----------------
// Unswapped orientation (coalesced fp32 stores). Q-frags resident in regs,
// K B-frags loaded DIRECTLY from global in fragment layout. No LDS staging.
// Interleaved key mapping (key = nbase + 2*l15 + nt) -> adjacent output cols
// -> float2 stores, 128B contiguous per quad-row.
__global__ __launch_bounds__(256, 4) void attn_p2(
    const short* __restrict__ Q, const short* __restrict__ K,
    const float* __restrict__ rws, float* __restrict__ wout)
{
    __shared__ float rinv[64];

    int tid = threadIdx.x, wave = tid >> 6, lane = tid & 63, quad = lane >> 4, l15 = lane & 15;
    int qt = blockIdx.x, bh = blockIdx.y;
    const short* qb  = Q + ((size_t)bh * SEQ + qt * 64) * DKH;
    const short* kbp = K + (size_t)bh * SEQ * DKH;

    if (tid < 64) rinv[tid] = rws[((size_t)bh * 32 + qt) * 64 + tid];

    // Q A-frags: qf[mt][kt] = Q[q=mt*16+l15][d=kt*32+quad*8 ..+7]
    short8 qf[4][2];
#pragma unroll
    for (int mt = 0; mt < 4; mt++)
#pragma unroll
        for (int kt = 0; kt < 2; kt++)
            qf[mt][kt] = *(const short8*)&qb[(mt * 16 + l15) * 64 + kt * 32 + quad * 8];
    __syncthreads();

    int nbase = wave * 32;
    float* wb = wout + ((size_t)bh * SEQ + qt * 64) * SEQ;

    for (int kb = 0; kb < SEQ / 128; kb++) {
        // K B-frags direct from global: key = kb*128 + nbase + 2*l15 + nt
        short8 bf[2][2];
#pragma unroll
        for (int nt = 0; nt < 2; nt++)
#pragma unroll
            for (int kt = 0; kt < 2; kt++)
                bf[nt][kt] = *(const short8*)&kbp[(size_t)(kb * 128 + nbase + 2 * l15 + nt) * 64 + kt * 32 + quad * 8];

        floatx4 sacc[4][2];
#pragma unroll
        for (int mt = 0; mt < 4; mt++)
#pragma unroll
            for (int nt = 0; nt < 2; nt++) sacc[mt][nt] = (floatx4){0.f, 0.f, 0.f, 0.f};
#pragma unroll
        for (int kt = 0; kt < 2; kt++)
#pragma unroll
            for (int mt = 0; mt < 4; mt++)
#pragma unroll
                for (int nt = 0; nt < 2; nt++)
                    sacc[mt][nt] = __builtin_amdgcn_mfma_f32_16x16x32_bf16(qf[mt][kt], bf[nt][kt], sacc[mt][nt], 0, 0, 0);
#pragma unroll
        for (int mt = 0; mt < 4; mt++) {
#pragma unroll
            for (int r = 0; r < 4; r++) {
                int row = mt * 16 + quad * 4 + r;
                float ri = rinv[row];
                float2 w2;
                w2.x = __expf(sacc[mt][0][r] * 0.125f) * ri;
                w2.y = __expf(sacc[mt][1][r] * 0.125f) * ri;
                *(float2*)&wb[(size_t)row * SEQ + kb * 128 + nbase + 2 * l15] = w2;
            }
        }
    }
}

extern "C" void kernel_launch(void* const* d_in, const int* in_sizes, int n_in,
                              void* d_out, int out_size, void* d_ws, size_t ws_size,
                              hipStream_t stream) {
    const float* query = (const float*)d_in[0];
    const float* key_  = (const float*)d_in[1];
    const float* value = (const float*)d_in[2];
    const float* Wq = (const float*)d_in[3];  const float* bq = (const float*)d_in[4];
    const float* Wk = (const float*)d_in[5];  const float* bk = (const float*)d_in[6];
    const float* Wv = (const float*)d_in[7];  const float* bv = (const float*)d_in[8];
    const float* Wo = (const float*)d_in[9];  const float* bo = (const float*)d_in[10];

    char* ws = (char*)d_ws;
    const size_t MB = 1ull << 20;
    short* xq  = (short*)(ws +  0 * MB);   // [4096,1024] bf16 (dead after gemm_qkv)
    short* xk  = (short*)(ws +  8 * MB);
    short* xv  = (short*)(ws + 16 * MB);
    short* wtq = (short*)(ws + 24 * MB);   // [1024(n),1024(k)] bf16
    short* wtk = (short*)(ws + 26 * MB);
    short* wtv = (short*)(ws + 28 * MB);
    short* wto = (short*)(ws + 30 * MB);
    short* qh  = (short*)(ws + 32 * MB);   // [B,H,S,64] bf16
    short* kh  = (short*)(ws + 40 * MB);
    short* vth = (short*)(ws + 48 * MB);   // [B,H,64,S] bf16
    short* ctx = (short*)(ws + 56 * MB);   // [4096,1024] bf16
    float* rws = (float*)(ws +  0 * MB);   // [32,32,64] rinv — reuses dead xq region

    float* out0 = (float*)d_out;
    float* wout = out0 + (size_t)4194304;

    conv3<<<dim3(4096, 1, 3), 256, 0, stream>>>(query, key_, value, xq, xk, xv);
    conv_wt4<<<dim3(16, 16, 4), 256, 0, stream>>>(Wq, Wk, Wv, Wo, wtq, wtk, wtv, wto);

    gemm_qkv<<<dim3(16, 32, 3), 256, 0, stream>>>(xq, xk, xv, wtq, wtk, wtv,
                                                  bq, bk, bv, qh, kh, vth);

    attn_p1<<<dim3(SEQ / 64, 32), 256, 0, stream>>>(qh, kh, vth, rws, ctx);
    attn_p2<<<dim3(SEQ / 64, 32), 256, 0, stream>>>(qh, kh, rws, wout);

    gemm_fin<<<dim3(16, 32), 256, 0, stream>>>(ctx, wto, bo, out0);
}